// Round 12
// baseline (308.970 us; speedup 1.0000x reference)
//
#include <hip/hip_runtime.h>
#include <math.h>

#define B_ 8
#define T_ 4096
#define D_ 192
#define E_ 6
#define H_ 768            // 4*D
#define NTOK (B_*T_)      // 32768
#define NT 3              // expert types
#define TPB 64            // tokens per GEMM block pair
#define NNT 48            // rw1 column-tiles (nw1 handled in router_post)
#define NG  24            // tiles per half
#define NKS 6             // K steps of 32 (K=192)
#define TT2 16            // tokens per router_post block

// ws float-offset layout
#define WS_TPART 0        // 3*768 (rb1 folded in)
#define WS_W2M   2304     // 768
#define WS_TEMP  3072
#define WS_RB2M  3073
#define WS_ENT   3074
#define WS_LOAD  3075     // 6 uints
#define WS_BP    4096     // bf16 fragment pack: 48 * 9216 ushorts (884 KB)
#define WS_LOGP  225280   // partial logits: 32768*3 f32 (384 KB), zeroed each call

typedef float  f32x4  __attribute__((ext_vector_type(4)));
typedef short  bf16x8 __attribute__((ext_vector_type(8)));

__device__ __forceinline__ ushort bf16rn(float f) {   // round-to-nearest-even bf16
    unsigned u = __float_as_uint(f);
    return (ushort)((u + 0x7FFFu + ((u >> 16) & 1u)) >> 16);
}

// Fast erf (Abramowitz-Stegun 7.1.26): |err| <= 1.5e-7 (validated R4-R11).
__device__ __forceinline__ float gelu_f(float v) {
    float x  = v * 0.70710678118654752440f;
    float ax = fabsf(x);
    float t  = __builtin_amdgcn_rcpf(fmaf(0.3275911f, ax, 1.0f));
    float y  = t * fmaf(t, fmaf(t, fmaf(t, fmaf(t, 1.061405429f, -1.453152027f),
                                         1.421413741f), -0.284496736f), 0.254829592f);
    float em = __expf(-ax * ax);
    float er = fmaf(-y, em, 1.0f);
    er = copysignf(er, x);
    return 0.5f * v * (1.0f + er);
}
__device__ __forceinline__ float softplus_f(float x) {
    return fmaxf(x, 0.0f) + log1pf(expf(-fabsf(x)));
}

// prep grid (154 blocks): [0,48) pack B frags; [48,57) tpart; 57 w2m+scalars;
// [58,154) zero the partial-logit buffer (96 blocks x 1024 floats).
__global__ __launch_bounds__(256) void prep_kernel(
    const float* __restrict__ type_emb,    // (3, 384)
    const float* __restrict__ rw1,         // (576, 768)
    const float* __restrict__ rb1,         // (768)
    const float* __restrict__ rw2,         // (768, 6)
    const float* __restrict__ rb2,         // (6)
    const float* __restrict__ temperature, // (1)
    float* __restrict__ wsF)
{
    int blk = blockIdx.x, tid = threadIdx.x;
    if (blk < NNT) {
        int nt = blk;
        ushort* Bp = (ushort*)(wsF + WS_BP);
        int col = tid & 15;                         // coalesced reads: 16 cols/row
        for (int kr = tid >> 4; kr < D_; kr += 16) {
            float a = rw1[(size_t)kr * H_ + nt * 16 + col];
            ushort s1 = bf16rn(a);  float f1 = __uint_as_float((unsigned)s1 << 16);
            float r1 = a - f1;
            ushort s2 = bf16rn(r1); float f2 = __uint_as_float((unsigned)s2 << 16);
            float r2 = r1 - f2;
            ushort s3 = bf16rn(r2);
            // B-frag layout: lane l holds B[k= ks*32+(l>>4)*8+i][col= l&15]
            int ks = kr >> 5, kg = (kr >> 3) & 3, i = kr & 7;
            int l  = (kg << 4) | col;
            size_t base = (size_t)nt * 9216 + (size_t)((ks * 3) * 64 + l) * 8 + i;
            Bp[base]        = s1;                   // spl 0
            Bp[base + 512]  = s2;                   // spl 1 (+64 lanes*8)
            Bp[base + 1024] = s3;                   // spl 2
        }
    } else if (blk < NNT + 9) {
        int o = (blk - NNT) * 256 + tid;            // 0..2303
        int c = o / H_, j = o % H_;
        float s = rb1[j];
        const float* te = type_emb + c * (2 * D_);
        #pragma unroll 4
        for (int k = 0; k < 2 * D_; ++k)
            s = fmaf(te[k], rw1[(size_t)(D_ + k) * H_ + j], s);
        wsF[WS_TPART + o] = s;
    } else if (blk == NNT + 9) {
        for (int j = tid; j < H_; j += 256) {
            float s = 0.f;
            #pragma unroll
            for (int e = 0; e < E_; ++e) s += rw2[(size_t)j * E_ + e];
            wsF[WS_W2M + j] = s * (1.0f / 6.0f);
        }
        if (tid == 0) {
            float decay = (float)pow(0.95, (double)(T_ / 100));   // 0.95^40
            float tv = temperature[0] * decay;
            wsF[WS_TEMP] = fminf(fmaxf(tv, 0.05f), 3.0f);
            float rs = 0.f;
            #pragma unroll
            for (int e = 0; e < E_; ++e) rs += rb2[e];
            wsF[WS_RB2M] = rs * (1.0f / 6.0f);
            wsF[WS_ENT] = 0.f;
            unsigned* lu = (unsigned*)(wsF + WS_LOAD);
            #pragma unroll
            for (int e = 0; e < E_; ++e) lu[e] = 0u;
        }
    } else {
        // zero WS_LOGP: deterministic re-init every call (graph replays)
        int idx = (blk - (NNT + 10)) * 256 + tid;   // float4 index
        float4 z = {0.f, 0.f, 0.f, 0.f};
        ((float4*)(wsF + WS_LOGP))[idx] = z;
    }
}

// R12: tile-split GEMM. Block pair (2m,2m+1) = same 64 tokens, halves of the
// 48 tiles (bid&1). Grid 1024 -> 4 blocks/CU (R8/R10 were GRID-limited to
// 2/CU: 512 blocks / 256 CU). 16 waves/CU = 2x TLP at the R10-proven 256-thread
// VGPR footprint ((512,4) in R11 spilled: 64-VGPR cap vs ~110 live). Partial
// logits -> atomicAdd; exactly 2 contributions/address => IEEE-commutative
// => deterministic. R10's single-barrier double-buffer loop kept verbatim.
__global__ __launch_bounds__(256, 4) void router_mfma(
    const float* __restrict__ x,            // (32768, 192)
    float* __restrict__ wsF)
{
    __shared__ float4 Bst[2][1152];     // 36 KB double-buffered B tile (only LDS)

    int tid = threadIdx.x;
    int wave = tid >> 6, lane = tid & 63;
    int pairid = blockIdx.x >> 1;
    int half   = blockIdx.x & 1;
    int tok0   = pairid * TPB;
    int jc = lane & 15;

    // ---- A fragments: lane holds token row tok0+wave*16+jc, k=ks*32+(lane>>4)*8+i.
    // 3-way bf16 split (72 VGPR, loop-invariant).
    int tok = tok0 + (wave << 4) + jc;
    int kg  = (lane >> 4) << 3;
    bf16x8 a1[NKS], a2[NKS], a3[NKS];
    #pragma unroll
    for (int ks = 0; ks < NKS; ++ks) {
        const float* xp = x + (size_t)tok * D_ + ks * 32 + kg;
        float4 v0 = *(const float4*)xp;
        float4 v1 = *(const float4*)(xp + 4);
        float f[8] = {v0.x, v0.y, v0.z, v0.w, v1.x, v1.y, v1.z, v1.w};
        #pragma unroll
        for (int i = 0; i < 8; ++i) {
            float a = f[i];
            ushort s1 = bf16rn(a);  float f1 = __uint_as_float((unsigned)s1 << 16);
            float r1 = a - f1;
            ushort s2 = bf16rn(r1); float f2 = __uint_as_float((unsigned)s2 << 16);
            float r2 = r1 - f2;
            a1[ks][i] = (short)s1; a2[ks][i] = (short)s2; a3[ks][i] = (short)bf16rn(r2);
        }
    }

    float la0[4] = {0,0,0,0}, la1[4] = {0,0,0,0}, la2[4] = {0,0,0,0};
    const ushort* Bp = (const ushort*)(wsF + WS_BP);

    int base = half * NG;
    int rot  = (blockIdx.x >> 3) % NG;   // decorrelate co-XCD blocks (R6 lesson)

    float4 g0, g1, g2, g3, g4;           // reg staging
#define STAGE_LOAD(ntv) { \
    const float4* sp_ = (const float4*)(Bp + (size_t)(ntv) * 9216); \
    g0 = sp_[tid]; g1 = sp_[tid + 256]; g2 = sp_[tid + 512]; g3 = sp_[tid + 768]; \
    if (tid < 128) g4 = sp_[tid + 1024]; }
#define STAGE_WRITE(buf) { \
    (buf)[tid] = g0; (buf)[tid + 256] = g1; (buf)[tid + 512] = g2; (buf)[tid + 768] = g3; \
    if (tid < 128) (buf)[tid + 1024] = g4; }

    STAGE_LOAD(base + rot);
    STAGE_WRITE(Bst[0]);
    __syncthreads();

    int buf = 0;
    for (int it = 0; it < NG; ++it) {
        int nt = base + ((rot + it >= NG) ? (rot + it - NG) : (rot + it));
        if (it + 1 < NG) {
            int itn = rot + it + 1;
            int ntn = base + ((itn >= NG) ? itn - NG : itn);
            STAGE_LOAD(ntn);
        }

        const bf16x8* bp = (const bf16x8*)&Bst[buf][0];
        f32x4 c0 = {0,0,0,0}, c1 = {0,0,0,0}, c2 = {0,0,0,0},
              c3 = {0,0,0,0}, c4 = {0,0,0,0}, c5 = {0,0,0,0};
        #pragma unroll
        for (int ks = 0; ks < NKS; ++ks) {
            bf16x8 b1 = bp[(ks * 3 + 0) * 64 + lane];
            bf16x8 b2 = bp[(ks * 3 + 1) * 64 + lane];
            bf16x8 b3 = bp[(ks * 3 + 2) * 64 + lane];
            c0 = __builtin_amdgcn_mfma_f32_16x16x32_bf16(a1[ks], b1, c0, 0, 0, 0);
            c1 = __builtin_amdgcn_mfma_f32_16x16x32_bf16(a1[ks], b2, c1, 0, 0, 0);
            c2 = __builtin_amdgcn_mfma_f32_16x16x32_bf16(a2[ks], b1, c2, 0, 0, 0);
            c3 = __builtin_amdgcn_mfma_f32_16x16x32_bf16(a2[ks], b2, c3, 0, 0, 0);
            c4 = __builtin_amdgcn_mfma_f32_16x16x32_bf16(a1[ks], b3, c4, 0, 0, 0);
            c5 = __builtin_amdgcn_mfma_f32_16x16x32_bf16(a3[ks], b1, c5, 0, 0, 0);
        }
        // D layout: row=(lane>>4)*4+r (token-local), col=lane&15 (j within tile)
        {
            int j = nt * 16 + jc;
            float w2v = wsF[WS_W2M + j];          // global, L1-resident
            float t0  = wsF[WS_TPART + j];
            float t1  = wsF[WS_TPART + H_ + j];
            float t2  = wsF[WS_TPART + 2 * H_ + j];
            #pragma unroll
            for (int r = 0; r < 4; ++r) {
                float xv = ((c0[r] + c1[r]) + (c2[r] + c3[r])) + (c4[r] + c5[r]);
                la0[r] += gelu_f(xv + t0) * w2v;
                la1[r] += gelu_f(xv + t1) * w2v;
                la2[r] += gelu_f(xv + t2) * w2v;
            }
        }

        if (it + 1 < NG) STAGE_WRITE(Bst[buf ^ 1]);
        __syncthreads();            // single barrier per tile (R10-verified)
        buf ^= 1;
    }

    // ---- partial logits: 16-lane butterfly, then 2-way atomic combine
    #pragma unroll
    for (int r = 0; r < 4; ++r) {
        float v0 = la0[r], v1 = la1[r], v2 = la2[r];
        #pragma unroll
        for (int off = 1; off < 16; off <<= 1) {
            v0 += __shfl_xor(v0, off, 64);
            v1 += __shfl_xor(v1, off, 64);
            v2 += __shfl_xor(v2, off, 64);
        }
        if (jc == 0) {
            int t = tok0 + (wave << 4) + ((lane >> 4) << 2) + r;
            atomicAdd(&wsF[WS_LOGP + (size_t)t * NT + 0], v0);
            atomicAdd(&wsF[WS_LOGP + (size_t)t * NT + 1], v1);
            atomicAdd(&wsF[WS_LOGP + (size_t)t * NT + 2], v2);
        }
    }
}

// R12 phase 3 (standalone): R5's verified structure. Noise MLP from x via LDS,
// logits = summed partials + rb2m, top-2, softmax, entropy, outputs.
__global__ __launch_bounds__(256) void router_post(
    const float* __restrict__ x,            // (32768, 192)
    const float* __restrict__ noise,        // (32768, 6)
    const int*   __restrict__ expert_types, // (6)
    const float* __restrict__ nw1,          // (192, 12)
    const float* __restrict__ nb1,          // (12)
    const float* __restrict__ nw2,          // (12, 6)
    const float* __restrict__ nb2,          // (6)
    float* __restrict__ wsF,
    float* __restrict__ out)
{
    __shared__ float xsT[D_][TT2];      // 12 KB
    __shared__ float h1[TT2][12];
    __shared__ float noisyL[TT2][E_];
    __shared__ float psL[TT2][2];
    __shared__ int   isL[TT2][2];
    __shared__ float entL[TT2];
    __shared__ unsigned loadL[E_];

    int tid = threadIdx.x;
    int tok0 = blockIdx.x * TT2;

    for (int i = tid; i < TT2 * D_; i += 256) {
        int t = i / D_, k = i % D_;
        xsT[k][t] = x[(size_t)tok0 * D_ + i];
    }
    if (tid < E_) loadL[tid] = 0u;
    __syncthreads();

    int t = tid >> 4, j = tid & 15;       // 16 threads per token
    if (j < 12) {
        float s = nb1[j];
        #pragma unroll 4
        for (int k = 0; k < D_; ++k) s = fmaf(xsT[k][t], nw1[k * 12 + j], s);
        h1[t][j] = gelu_f(s);
    }
    __syncthreads();
    float temp = wsF[WS_TEMP];
    float rb2m = wsF[WS_RB2M];
    if (j < E_) {
        float s = nb2[j];
        #pragma unroll
        for (int i2 = 0; i2 < 12; ++i2) s = fmaf(h1[t][i2], nw2[i2 * E_ + j], s);
        float nsc = softplus_f(softplus_f(s));
        int ety = expert_types[j];
        float lg = wsF[WS_LOGP + (size_t)(tok0 + t) * NT + ety] + rb2m;
        noisyL[t][j] = lg + ((ety == 1) ? 0.3f : 0.0f)
                     + temp * (noise[(size_t)(tok0 + t) * E_ + j] * nsc);
    }
    __syncthreads();
    if (j == 0) {
        // top-2, ties -> lower index first (strict > keeps earliest)
        float v1 = -1e30f; int i1 = 0;
        #pragma unroll
        for (int e = 0; e < E_; ++e) {
            float v = noisyL[t][e];
            if (v > v1) { v1 = v; i1 = e; }
        }
        float v2 = -1e30f; int i2 = 0;
        #pragma unroll
        for (int e = 0; e < E_; ++e) {
            if (e == i1) continue;
            float v = noisyL[t][e];
            if (v > v2) { v2 = v; i2 = e; }
        }
        float e2 = expf(v2 - v1);
        float den = 1.0f + e2;
        float p1 = 1.0f / den, p2 = e2 / den;
        psL[t][0] = p1; psL[t][1] = p2;
        isL[t][0] = i1; isL[t][1] = i2;
        entL[t] = -(p1 * logf(p1 + 1e-8f) + p2 * logf(p2 + 1e-8f));
        atomicAdd(&loadL[i1], 1u);
        atomicAdd(&loadL[i2], 1u);
    }
    __syncthreads();

    for (int i = tid; i < TT2 * E_; i += 256) {
        int tt = i / E_, e = i % E_;
        float v = 0.f;
        if (e == isL[tt][0])      v = psL[tt][0];
        else if (e == isL[tt][1]) v = psL[tt][1];
        out[(size_t)tok0 * E_ + i] = v;
    }
    if (tid < TT2 * 2) {
        int tt = tid >> 1, s = tid & 1;
        out[(size_t)NTOK * E_ + (size_t)(tok0 + tt) * 2 + s] = (float)isL[tt][s];
    }
    if (tid == 0) {
        float es = 0.f;
        #pragma unroll
        for (int tt = 0; tt < TT2; ++tt) es += entL[tt];
        atomicAdd(&wsF[WS_ENT], es);
        unsigned* lu = (unsigned*)(wsF + WS_LOAD);
        #pragma unroll
        for (int e = 0; e < E_; ++e)
            if (loadL[e]) atomicAdd(&lu[e], loadL[e]);
    }
}

__global__ void finalize_kernel(const float* __restrict__ wsF,
                                float* __restrict__ out)
{
    if (threadIdx.x == 0 && blockIdx.x == 0) {
        const unsigned* lu = (const unsigned*)(wsF + WS_LOAD);
        double m = 0.0, l[E_];
        #pragma unroll
        for (int e = 0; e < E_; ++e) { l[e] = (double)lu[e]; m += l[e]; }
        m /= (double)E_;
        double var = 0.0;
        #pragma unroll
        for (int e = 0; e < E_; ++e) { double d = l[e] - m; var += d * d; }
        var /= (double)(E_ - 1);
        double stdl = sqrt(var);
        // std(importance) == 0 exactly (top-2 always picks 2 of 6)
        double ent = (double)wsF[WS_ENT] / (double)NTOK;
        out[(size_t)NTOK * E_ + (size_t)NTOK * 2] = (float)(0.1 * ent + 0.2 * stdl);
    }
}

extern "C" void kernel_launch(void* const* d_in, const int* in_sizes, int n_in,
                              void* d_out, int out_size, void* d_ws, size_t ws_size,
                              hipStream_t stream)
{
    const float* x            = (const float*)d_in[0];
    const float* noise        = (const float*)d_in[1];
    const int*   expert_types = (const int*)  d_in[2];
    const float* type_emb     = (const float*)d_in[3];
    const float* nw1          = (const float*)d_in[4];
    const float* nb1          = (const float*)d_in[5];
    const float* nw2          = (const float*)d_in[6];
    const float* nb2          = (const float*)d_in[7];
    const float* rw1          = (const float*)d_in[8];
    const float* rb1          = (const float*)d_in[9];
    const float* rw2          = (const float*)d_in[10];
    const float* rb2          = (const float*)d_in[11];
    const float* temperature  = (const float*)d_in[12];
    float* out = (float*)d_out;
    float* wsF = (float*)d_ws;

    prep_kernel<<<NNT + 10 + 96, 256, 0, stream>>>(type_emb, rw1, rb1, rw2, rb2,
                                                   temperature, wsF);
    router_mfma<<<(NTOK / TPB) * 2, 256, 0, stream>>>(x, wsF);
    router_post<<<NTOK / TT2, 256, 0, stream>>>(x, noise, expert_types,
                                                nw1, nb1, nw2, nb2, wsF, out);
    finalize_kernel<<<1, 64, 0, stream>>>(wsF, out);
}

// Round 13
// 157.914 us; speedup vs baseline: 1.9566x; 1.9566x over previous
//
#include <hip/hip_runtime.h>
#include <math.h>

#define B_ 8
#define T_ 4096
#define D_ 192
#define E_ 6
#define H_ 768            // 4*D
#define NTOK (B_*T_)      // 32768
#define NT 3              // expert types
#define TPB 64            // tokens per block
#define NBLK (NTOK/TPB)   // 512
#define NNT 49            // 48 rw1 column-tiles + 1 padded nw1 tile
#define NKS 6             // K steps of 32 (K=192)

// ws float-offset layout
#define WS_TPART 0        // 3*768 (rb1 folded in)
#define WS_W2M   2304     // 768
#define WS_TEMP  3072
#define WS_RB2M  3073
#define WS_ENT   3074
#define WS_LOAD  3075     // 6 uints
#define WS_BP    4096     // bf16 fragment pack: 49 * 9216 ushorts (903 KB)

typedef float  f32x4  __attribute__((ext_vector_type(4)));
typedef short  bf16x8 __attribute__((ext_vector_type(8)));

__device__ __forceinline__ ushort bf16rn(float f) {   // round-to-nearest-even bf16
    unsigned u = __float_as_uint(f);
    return (ushort)((u + 0x7FFFu + ((u >> 16) & 1u)) >> 16);
}

// Fast erf (Abramowitz-Stegun 7.1.26): |err| <= 1.5e-7 (validated R4-R12).
__device__ __forceinline__ float gelu_f(float v) {
    float x  = v * 0.70710678118654752440f;
    float ax = fabsf(x);
    float t  = __builtin_amdgcn_rcpf(fmaf(0.3275911f, ax, 1.0f));
    float y  = t * fmaf(t, fmaf(t, fmaf(t, fmaf(t, 1.061405429f, -1.453152027f),
                                         1.421413741f), -0.284496736f), 0.254829592f);
    float em = __expf(-ax * ax);
    float er = fmaf(-y, em, 1.0f);
    er = copysignf(er, x);
    return 0.5f * v * (1.0f + er);
}
__device__ __forceinline__ float softplus_f(float x) {
    return fmaxf(x, 0.0f) + log1pf(expf(-fabsf(x)));
}

// prep: blocks 0..48 pack B fragments (3-way bf16 split, MFMA lane order);
// blocks 49..57 tpart; block 58 w2m + scalars.
__global__ __launch_bounds__(256) void prep_kernel(
    const float* __restrict__ type_emb,    // (3, 384)
    const float* __restrict__ rw1,         // (576, 768)
    const float* __restrict__ rb1,         // (768)
    const float* __restrict__ rw2,         // (768, 6)
    const float* __restrict__ rb2,         // (6)
    const float* __restrict__ temperature, // (1)
    const float* __restrict__ nw1,         // (192, 12)
    float* __restrict__ wsF)
{
    int blk = blockIdx.x, tid = threadIdx.x;
    if (blk < NNT) {
        int nt = blk;
        ushort* Bp = (ushort*)(wsF + WS_BP);
        int col = tid & 15;                         // coalesced reads: 16 cols/row
        for (int kr = tid >> 4; kr < D_; kr += 16) {
            float a;
            if (nt < 48) a = rw1[(size_t)kr * H_ + nt * 16 + col];
            else         a = (col < 12) ? nw1[kr * 12 + col] : 0.0f;
            ushort s1 = bf16rn(a);  float f1 = __uint_as_float((unsigned)s1 << 16);
            float r1 = a - f1;
            ushort s2 = bf16rn(r1); float f2 = __uint_as_float((unsigned)s2 << 16);
            float r2 = r1 - f2;
            ushort s3 = bf16rn(r2);
            // B-frag layout: lane l holds B[k= ks*32+(l>>4)*8+i][col= l&15]
            int ks = kr >> 5, kg = (kr >> 3) & 3, i = kr & 7;
            int l  = (kg << 4) | col;
            size_t base = (size_t)nt * 9216 + (size_t)((ks * 3) * 64 + l) * 8 + i;
            Bp[base]        = s1;                   // spl 0
            Bp[base + 512]  = s2;                   // spl 1 (+64 lanes*8)
            Bp[base + 1024] = s3;                   // spl 2
        }
    } else if (blk < NNT + 9) {
        int o = (blk - NNT) * 256 + tid;            // 0..2303
        int c = o / H_, j = o % H_;
        float s = rb1[j];
        const float* te = type_emb + c * (2 * D_);
        #pragma unroll 4
        for (int k = 0; k < 2 * D_; ++k)
            s = fmaf(te[k], rw1[(size_t)(D_ + k) * H_ + j], s);
        wsF[WS_TPART + o] = s;
    } else {
        for (int j = tid; j < H_; j += 256) {
            float s = 0.f;
            #pragma unroll
            for (int e = 0; e < E_; ++e) s += rw2[(size_t)j * E_ + e];
            wsF[WS_W2M + j] = s * (1.0f / 6.0f);
        }
        if (tid == 0) {
            float decay = (float)pow(0.95, (double)(T_ / 100));   // 0.95^40
            float tv = temperature[0] * decay;
            wsF[WS_TEMP] = fminf(fmaxf(tv, 0.05f), 3.0f);
            float rs = 0.f;
            #pragma unroll
            for (int e = 0; e < E_; ++e) rs += rb2[e];
            wsF[WS_RB2M] = rs * (1.0f / 6.0f);
            wsF[WS_ENT] = 0.f;
            unsigned* lu = (unsigned*)(wsF + WS_LOAD);
            #pragma unroll
            for (int e = 0; e < E_; ++e) lu[e] = 0u;
        }
    }
}

// R13: R10 structure (fused, 512 blocks — best measured) + two in-wave ILP
// changes targeting the per-tile serial chain (R12 isolation: GEMM ~120us is
// occupancy-INVARIANT at 2 vs 4 blocks/CU, so the chain, not TLP, is the
// bound): (1) gelu epilogue deferred one tile — its ~300cy of independent
// VALU interleaves with the current tile's ds_read/MFMA wait gaps instead of
// running serially after; (2) 6 split-products chained into 3 MFMA
// accumulators (smallest-first), -12 VGPR, -20 adds/tile. (256,2): no cap.
__global__ __launch_bounds__(256, 2) void router_mfma(
    const float* __restrict__ x,            // (32768, 192)
    const float* __restrict__ noise,        // (32768, 6)
    const int*   __restrict__ expert_types, // (6)
    const float* __restrict__ nb1,          // (12)
    const float* __restrict__ nw2,          // (12, 6)
    const float* __restrict__ nb2,          // (6)
    float* __restrict__ wsF,
    float* __restrict__ out)
{
    __shared__ float4 Bst[2][1152];     // 36 KB double-buffered B tile
    __shared__ float tpL[NT * H_];      // 9 KB
    __shared__ float w2L[H_];           // 3 KB
    __shared__ float logitsL[TPB][NT];
    __shared__ float h1L[TPB][12];
    __shared__ float noisyL[TPB][E_];
    __shared__ float psL[TPB][2];
    __shared__ int   isL[TPB][2];
    __shared__ float entL[TPB];
    __shared__ unsigned loadL[E_];

    int tid = threadIdx.x;
    int wave = tid >> 6, lane = tid & 63;
    int tok0 = blockIdx.x * TPB;
    int jc = lane & 15;

    for (int i = tid; i < NT * H_; i += 256) tpL[i] = wsF[WS_TPART + i];
    for (int i = tid; i < H_; i += 256)      w2L[i] = wsF[WS_W2M + i];
    if (tid < E_) loadL[tid] = 0u;

    // ---- A fragments: lane holds token row tok0+wave*16+jc, k=ks*32+(lane>>4)*8+i.
    int tok = tok0 + (wave << 4) + jc;
    int kg  = (lane >> 4) << 3;
    bf16x8 a1[NKS], a2[NKS], a3[NKS];
    #pragma unroll
    for (int ks = 0; ks < NKS; ++ks) {
        const float* xp = x + (size_t)tok * D_ + ks * 32 + kg;
        float4 v0 = *(const float4*)xp;
        float4 v1 = *(const float4*)(xp + 4);
        float f[8] = {v0.x, v0.y, v0.z, v0.w, v1.x, v1.y, v1.z, v1.w};
        #pragma unroll
        for (int i = 0; i < 8; ++i) {
            float a = f[i];
            ushort s1 = bf16rn(a);  float f1 = __uint_as_float((unsigned)s1 << 16);
            float r1 = a - f1;
            ushort s2 = bf16rn(r1); float f2 = __uint_as_float((unsigned)s2 << 16);
            float r2 = r1 - f2;
            a1[ks][i] = (short)s1; a2[ks][i] = (short)s2; a3[ks][i] = (short)bf16rn(r2);
        }
    }

    float la0[4] = {0,0,0,0}, la1[4] = {0,0,0,0}, la2[4] = {0,0,0,0};
    const ushort* Bp = (const ushort*)(wsF + WS_BP);
    int nt0 = blockIdx.x % NNT;    // decorrelate co-XCD blocks (R6 lesson)

    float4 g0, g1, g2, g3, g4;     // reg staging (load-early / write-late)
#define STAGE_LOAD(ntv) { \
    const float4* sp_ = (const float4*)(Bp + (size_t)(ntv) * 9216); \
    g0 = sp_[tid]; g1 = sp_[tid + 256]; g2 = sp_[tid + 512]; g3 = sp_[tid + 768]; \
    if (tid < 128) g4 = sp_[tid + 1024]; }
#define STAGE_WRITE(buf) { \
    (buf)[tid] = g0; (buf)[tid + 256] = g1; (buf)[tid + 512] = g2; (buf)[tid + 768] = g3; \
    if (tid < 128) (buf)[tid + 1024] = g4; }

    // deferred-epilogue state: prev tile's accumulators + id
    f32x4 p1 = {0,0,0,0}, p2 = {0,0,0,0}, p3 = {0,0,0,0};
    int ntprev = -1;

#define EPILOGUE(P1, P2, P3, NTP) { \
    if ((NTP) < 48) { \
        int j_ = (NTP) * 16 + jc; \
        float w2v_ = w2L[j_]; \
        float t0_ = tpL[j_], t1_ = tpL[H_ + j_], t2_ = tpL[2 * H_ + j_]; \
        _Pragma("unroll") \
        for (int r_ = 0; r_ < 4; ++r_) { \
            float xv_ = ((P1)[r_] + (P2)[r_]) + (P3)[r_]; \
            la0[r_] += gelu_f(xv_ + t0_) * w2v_; \
            la1[r_] += gelu_f(xv_ + t1_) * w2v_; \
            la2[r_] += gelu_f(xv_ + t2_) * w2v_; \
        } \
    } else if (jc < 12) { \
        float bb_ = nb1[jc]; \
        _Pragma("unroll") \
        for (int r_ = 0; r_ < 4; ++r_) { \
            float xv_ = ((P1)[r_] + (P2)[r_]) + (P3)[r_]; \
            int tl_ = (wave << 4) + ((lane >> 4) << 2) + r_; \
            h1L[tl_][jc] = gelu_f(xv_ + bb_); \
        } \
    } }

    STAGE_LOAD(nt0);
    STAGE_WRITE(Bst[0]);
    __syncthreads();

    int cur = 0;
    for (int it = 0; it < NNT; ++it) {
        int nt = nt0 + it; if (nt >= NNT) nt -= NNT;
        if (it + 1 < NNT) { int ntn = nt + 1; if (ntn >= NNT) ntn -= NNT; STAGE_LOAD(ntn); }

        // deferred epilogue of tile it-1: pure-VALU, independent of this
        // tile's ds_read/MFMA -> scheduler fills the lgkm wait gaps with it.
        if (ntprev >= 0) EPILOGUE(p1, p2, p3, ntprev);

        const bf16x8* bp = (const bf16x8*)&Bst[cur][0];
        f32x4 cb1 = {0,0,0,0}, cb2 = {0,0,0,0}, cb3 = {0,0,0,0};
        #pragma unroll
        for (int ks = 0; ks < NKS; ++ks) {
            bf16x8 b1 = bp[(ks * 3 + 0) * 64 + lane];
            bf16x8 b2 = bp[(ks * 3 + 1) * 64 + lane];
            bf16x8 b3 = bp[(ks * 3 + 2) * 64 + lane];
            // chained accumulate, smallest terms first (precision)
            cb1 = __builtin_amdgcn_mfma_f32_16x16x32_bf16(a3[ks], b1, cb1, 0, 0, 0);
            cb1 = __builtin_amdgcn_mfma_f32_16x16x32_bf16(a2[ks], b1, cb1, 0, 0, 0);
            cb1 = __builtin_amdgcn_mfma_f32_16x16x32_bf16(a1[ks], b1, cb1, 0, 0, 0);
            cb2 = __builtin_amdgcn_mfma_f32_16x16x32_bf16(a2[ks], b2, cb2, 0, 0, 0);
            cb2 = __builtin_amdgcn_mfma_f32_16x16x32_bf16(a1[ks], b2, cb2, 0, 0, 0);
            cb3 = __builtin_amdgcn_mfma_f32_16x16x32_bf16(a1[ks], b3, cb3, 0, 0, 0);
        }
        p1 = cb1; p2 = cb2; p3 = cb3; ntprev = nt;

        if (it + 1 < NNT) STAGE_WRITE(Bst[cur ^ 1]);
        __syncthreads();            // single barrier per tile (R10-verified)
        cur ^= 1;
    }
    EPILOGUE(p1, p2, p3, ntprev);   // drain last tile

    // ---- finish logits: butterfly over the 16 j-columns held by a lane group
    float rb2m = wsF[WS_RB2M];
    #pragma unroll
    for (int r = 0; r < 4; ++r) {
        float v0 = la0[r], v1 = la1[r], v2 = la2[r];
        #pragma unroll
        for (int off = 1; off < 16; off <<= 1) {
            v0 += __shfl_xor(v0, off, 64);
            v1 += __shfl_xor(v1, off, 64);
            v2 += __shfl_xor(v2, off, 64);
        }
        if (jc == 0) {
            int tl = (wave << 4) + ((lane >> 4) << 2) + r;
            logitsL[tl][0] = v0 + rb2m;
            logitsL[tl][1] = v1 + rb2m;
            logitsL[tl][2] = v2 + rb2m;
        }
    }
    __syncthreads();

    // ---- phase 3: noise MLP layer 2, noisy logits, top-2, softmax, entropy
    float temp = wsF[WS_TEMP];
    for (int idx = tid; idx < TPB * E_; idx += 256) {
        int t = idx / E_, e = idx - t * E_;
        float s = nb2[e];
        #pragma unroll
        for (int i2 = 0; i2 < 12; ++i2) s = fmaf(h1L[t][i2], nw2[i2 * E_ + e], s);
        float nsc = softplus_f(softplus_f(s));
        int ety = expert_types[e];
        noisyL[t][e] = logitsL[t][ety] + ((ety == 1) ? 0.3f : 0.0f)
                     + temp * (noise[(size_t)(tok0 + t) * E_ + e] * nsc);
    }
    __syncthreads();
    if (tid < TPB) {
        int t = tid;
        float v1 = -1e30f; int i1 = 0;
        #pragma unroll
        for (int e = 0; e < E_; ++e) {
            float v = noisyL[t][e];
            if (v > v1) { v1 = v; i1 = e; }
        }
        float v2 = -1e30f; int i2 = 0;
        #pragma unroll
        for (int e = 0; e < E_; ++e) {
            if (e == i1) continue;
            float v = noisyL[t][e];
            if (v > v2) { v2 = v; i2 = e; }
        }
        float e2 = expf(v2 - v1);
        float den = 1.0f + e2;
        float p1s = 1.0f / den, p2s = e2 / den;
        psL[t][0] = p1s; psL[t][1] = p2s;
        isL[t][0] = i1; isL[t][1] = i2;
        entL[t] = -(p1s * logf(p1s + 1e-8f) + p2s * logf(p2s + 1e-8f));
        atomicAdd(&loadL[i1], 1u);
        atomicAdd(&loadL[i2], 1u);
    }
    __syncthreads();
    for (int idx = tid; idx < TPB * E_; idx += 256) {
        int t = idx / E_, e = idx - t * E_;
        float v = 0.f;
        if (e == isL[t][0])      v = psL[t][0];
        else if (e == isL[t][1]) v = psL[t][1];
        out[(size_t)tok0 * E_ + idx] = v;
    }
    if (tid < TPB * 2) {
        int t = tid >> 1, s = tid & 1;
        out[(size_t)NTOK * E_ + (size_t)(tok0 + t) * 2 + s] = (float)isL[t][s];
    }
    if (tid == 0) {
        float es = 0.f;
        #pragma unroll
        for (int tt = 0; tt < TPB; ++tt) es += entL[tt];
        atomicAdd(&wsF[WS_ENT], es);
        unsigned* lu = (unsigned*)(wsF + WS_LOAD);
        #pragma unroll
        for (int e = 0; e < E_; ++e)
            if (loadL[e]) atomicAdd(&lu[e], loadL[e]);
    }
}

__global__ void finalize_kernel(const float* __restrict__ wsF,
                                float* __restrict__ out)
{
    if (threadIdx.x == 0 && blockIdx.x == 0) {
        const unsigned* lu = (const unsigned*)(wsF + WS_LOAD);
        double m = 0.0, l[E_];
        #pragma unroll
        for (int e = 0; e < E_; ++e) { l[e] = (double)lu[e]; m += l[e]; }
        m /= (double)E_;
        double var = 0.0;
        #pragma unroll
        for (int e = 0; e < E_; ++e) { double d = l[e] - m; var += d * d; }
        var /= (double)(E_ - 1);
        double stdl = sqrt(var);
        // std(importance) == 0 exactly (top-2 always picks 2 of 6)
        double ent = (double)wsF[WS_ENT] / (double)NTOK;
        out[(size_t)NTOK * E_ + (size_t)NTOK * 2] = (float)(0.1 * ent + 0.2 * stdl);
    }
}

extern "C" void kernel_launch(void* const* d_in, const int* in_sizes, int n_in,
                              void* d_out, int out_size, void* d_ws, size_t ws_size,
                              hipStream_t stream)
{
    const float* x            = (const float*)d_in[0];
    const float* noise        = (const float*)d_in[1];
    const int*   expert_types = (const int*)  d_in[2];
    const float* type_emb     = (const float*)d_in[3];
    const float* nw1          = (const float*)d_in[4];
    const float* nb1          = (const float*)d_in[5];
    const float* nw2          = (const float*)d_in[6];
    const float* nb2          = (const float*)d_in[7];
    const float* rw1          = (const float*)d_in[8];
    const float* rb1          = (const float*)d_in[9];
    const float* rw2          = (const float*)d_in[10];
    const float* rb2          = (const float*)d_in[11];
    const float* temperature  = (const float*)d_in[12];
    float* out = (float*)d_out;
    float* wsF = (float*)d_ws;

    prep_kernel<<<NNT + 10, 256, 0, stream>>>(type_emb, rw1, rb1, rw2, rb2,
                                              temperature, nw1, wsF);
    router_mfma<<<NBLK, 256, 0, stream>>>(x, noise, expert_types,
                                          nb1, nw2, nb2, wsF, out);
    finalize_kernel<<<1, 64, 0, stream>>>(wsF, out);
}

// Round 14
// 156.375 us; speedup vs baseline: 1.9758x; 1.0098x over previous
//
#include <hip/hip_runtime.h>
#include <math.h>

#define B_ 8
#define T_ 4096
#define D_ 192
#define E_ 6
#define H_ 768            // 4*D
#define NTOK (B_*T_)      // 32768
#define NT 3              // expert types
#define TPB 64            // tokens per block
#define NBLK (NTOK/TPB)   // 512
#define NNT 49            // 48 rw1 column-tiles + 1 padded nw1 tile
#define NKS 6             // K steps of 32 (K=192)

// ws float-offset layout
#define WS_TPART 0        // 3*768 (rb1 folded in)
#define WS_W2M   2304     // 768
#define WS_TEMP  3072
#define WS_RB2M  3073
#define WS_ENT   3074
#define WS_LOAD  3075     // 6 uints
#define WS_BP    4096     // bf16 fragment pack: 49 * 9216 ushorts (903 KB)

typedef float  f32x4  __attribute__((ext_vector_type(4)));
typedef short  bf16x8 __attribute__((ext_vector_type(8)));

__device__ __forceinline__ ushort bf16rn(float f) {   // round-to-nearest-even bf16
    unsigned u = __float_as_uint(f);
    return (ushort)((u + 0x7FFFu + ((u >> 16) & 1u)) >> 16);
}

// async global->LDS, 16B per lane (dest = wave-uniform base + lane*16)
__device__ __forceinline__ void gll16(const void* g, void* lds) {
    __builtin_amdgcn_global_load_lds(
        (const __attribute__((address_space(1))) unsigned*)g,
        (__attribute__((address_space(3))) unsigned*)lds, 16, 0, 0);
}

// Fast erf (Abramowitz-Stegun 7.1.26): |err| <= 1.5e-7 (validated R4-R13).
__device__ __forceinline__ float gelu_f(float v) {
    float x  = v * 0.70710678118654752440f;
    float ax = fabsf(x);
    float t  = __builtin_amdgcn_rcpf(fmaf(0.3275911f, ax, 1.0f));
    float y  = t * fmaf(t, fmaf(t, fmaf(t, fmaf(t, 1.061405429f, -1.453152027f),
                                         1.421413741f), -0.284496736f), 0.254829592f);
    float em = __expf(-ax * ax);
    float er = fmaf(-y, em, 1.0f);
    er = copysignf(er, x);
    return 0.5f * v * (1.0f + er);
}
__device__ __forceinline__ float softplus_f(float x) {
    return fmaxf(x, 0.0f) + log1pf(expf(-fabsf(x)));
}

// prep: blocks 0..48 pack B fragments (3-way bf16 split, MFMA lane order);
// blocks 49..57 tpart; block 58 w2m + scalars.
__global__ __launch_bounds__(256) void prep_kernel(
    const float* __restrict__ type_emb,    // (3, 384)
    const float* __restrict__ rw1,         // (576, 768)
    const float* __restrict__ rb1,         // (768)
    const float* __restrict__ rw2,         // (768, 6)
    const float* __restrict__ rb2,         // (6)
    const float* __restrict__ temperature, // (1)
    const float* __restrict__ nw1,         // (192, 12)
    float* __restrict__ wsF)
{
    int blk = blockIdx.x, tid = threadIdx.x;
    if (blk < NNT) {
        int nt = blk;
        ushort* Bp = (ushort*)(wsF + WS_BP);
        int col = tid & 15;                         // coalesced reads: 16 cols/row
        for (int kr = tid >> 4; kr < D_; kr += 16) {
            float a;
            if (nt < 48) a = rw1[(size_t)kr * H_ + nt * 16 + col];
            else         a = (col < 12) ? nw1[kr * 12 + col] : 0.0f;
            ushort s1 = bf16rn(a);  float f1 = __uint_as_float((unsigned)s1 << 16);
            float r1 = a - f1;
            ushort s2 = bf16rn(r1); float f2 = __uint_as_float((unsigned)s2 << 16);
            float r2 = r1 - f2;
            ushort s3 = bf16rn(r2);
            // B-frag layout: lane l holds B[k= ks*32+(l>>4)*8+i][col= l&15]
            int ks = kr >> 5, kg = (kr >> 3) & 3, i = kr & 7;
            int l  = (kg << 4) | col;
            size_t base = (size_t)nt * 9216 + (size_t)((ks * 3) * 64 + l) * 8 + i;
            Bp[base]        = s1;                   // spl 0
            Bp[base + 512]  = s2;                   // spl 1 (+64 lanes*8)
            Bp[base + 1024] = s3;                   // spl 2
        }
    } else if (blk < NNT + 9) {
        int o = (blk - NNT) * 256 + tid;            // 0..2303
        int c = o / H_, j = o % H_;
        float s = rb1[j];
        const float* te = type_emb + c * (2 * D_);
        #pragma unroll 4
        for (int k = 0; k < 2 * D_; ++k)
            s = fmaf(te[k], rw1[(size_t)(D_ + k) * H_ + j], s);
        wsF[WS_TPART + o] = s;
    } else {
        for (int j = tid; j < H_; j += 256) {
            float s = 0.f;
            #pragma unroll
            for (int e = 0; e < E_; ++e) s += rw2[(size_t)j * E_ + e];
            wsF[WS_W2M + j] = s * (1.0f / 6.0f);
        }
        if (tid == 0) {
            float decay = (float)pow(0.95, (double)(T_ / 100));   // 0.95^40
            float tv = temperature[0] * decay;
            wsF[WS_TEMP] = fminf(fmaxf(tv, 0.05f), 3.0f);
            float rs = 0.f;
            #pragma unroll
            for (int e = 0; e < E_; ++e) rs += rb2[e];
            wsF[WS_RB2M] = rs * (1.0f / 6.0f);
            wsF[WS_ENT] = 0.f;
            unsigned* lu = (unsigned*)(wsF + WS_LOAD);
            #pragma unroll
            for (int e = 0; e < E_; ++e) lu[e] = 0u;
        }
    }
}

// R14: R10 base (best verified: 122us router) + (1) global_load_lds staging —
// deletes the ds_write half of staging (~9us LDS pipe), its VALU, and 20
// staging VGPRs (m151: gload_lds beats reg-staging at this tile shape); (2)
// gelu epilogue deferred one tile WITH the 6 independent accumulators kept
// (R13's regression was the 18-deep chained-MFMA dependency, -8us, not the
// deferral). Deferral gives the scheduler ~500cy of independent VALU to
// overlay the next tile's ds_read/MFMA waits.
__global__ __launch_bounds__(256, 2) void router_mfma(
    const float* __restrict__ x,            // (32768, 192)
    const float* __restrict__ noise,        // (32768, 6)
    const int*   __restrict__ expert_types, // (6)
    const float* __restrict__ nb1,          // (12)
    const float* __restrict__ nw2,          // (12, 6)
    const float* __restrict__ nb2,          // (6)
    float* __restrict__ wsF,
    float* __restrict__ out)
{
    __shared__ float4 Bst[2][1152];     // 36 KB double-buffered B tile
    __shared__ float tpL[NT * H_];      // 9 KB
    __shared__ float w2L[H_];           // 3 KB
    __shared__ float logitsL[TPB][NT];
    __shared__ float h1L[TPB][12];
    __shared__ float noisyL[TPB][E_];
    __shared__ float psL[TPB][2];
    __shared__ int   isL[TPB][2];
    __shared__ float entL[TPB];
    __shared__ unsigned loadL[E_];

    int tid = threadIdx.x;
    int wave = tid >> 6, lane = tid & 63;
    int tok0 = blockIdx.x * TPB;
    int jc = lane & 15;

    for (int i = tid; i < NT * H_; i += 256) tpL[i] = wsF[WS_TPART + i];
    for (int i = tid; i < H_; i += 256)      w2L[i] = wsF[WS_W2M + i];
    if (tid < E_) loadL[tid] = 0u;

    // ---- A fragments: lane holds token row tok0+wave*16+jc, k=ks*32+(lane>>4)*8+i.
    int tok = tok0 + (wave << 4) + jc;
    int kg  = (lane >> 4) << 3;
    bf16x8 a1[NKS], a2[NKS], a3[NKS];
    #pragma unroll
    for (int ks = 0; ks < NKS; ++ks) {
        const float* xp = x + (size_t)tok * D_ + ks * 32 + kg;
        float4 v0 = *(const float4*)xp;
        float4 v1 = *(const float4*)(xp + 4);
        float f[8] = {v0.x, v0.y, v0.z, v0.w, v1.x, v1.y, v1.z, v1.w};
        #pragma unroll
        for (int i = 0; i < 8; ++i) {
            float a = f[i];
            ushort s1 = bf16rn(a);  float f1 = __uint_as_float((unsigned)s1 << 16);
            float r1 = a - f1;
            ushort s2 = bf16rn(r1); float f2 = __uint_as_float((unsigned)s2 << 16);
            float r2 = r1 - f2;
            a1[ks][i] = (short)s1; a2[ks][i] = (short)s2; a3[ks][i] = (short)bf16rn(r2);
        }
    }

    float la0[4] = {0,0,0,0}, la1[4] = {0,0,0,0}, la2[4] = {0,0,0,0};
    const ushort* Bp = (const ushort*)(wsF + WS_BP);
    int nt0 = blockIdx.x % NNT;    // decorrelate co-XCD blocks (R6 lesson)

    // async staging: 18 chunks of 64 float4 per tile; wave w issues chunks
    // {w, w+4, w+8, w+12} and (w<2) chunk 16+w. LDS dest is wave-uniform
    // base + lane*16 (linear layout — gload_lds requirement, m104).
#define STAGE(ntv, bufv) { \
    const float4* sp_ = (const float4*)(Bp + (size_t)(ntv) * 9216); \
    float4* dp_ = &Bst[bufv][0]; \
    _Pragma("unroll") \
    for (int c_ = wave; c_ < 16; c_ += 4) \
        gll16(sp_ + (c_ * 64 + lane), dp_ + c_ * 64); \
    if (wave < 2) gll16(sp_ + ((16 + wave) * 64 + lane), dp_ + (16 + wave) * 64); \
}

    // deferred-epilogue state: prev tile's 6 accumulators + id (24 VGPR)
    f32x4 p0 = {0,0,0,0}, p1 = {0,0,0,0}, p2 = {0,0,0,0},
          p3 = {0,0,0,0}, p4 = {0,0,0,0}, p5 = {0,0,0,0};
    int ntprev = -1;

#define EPILOGUE(NTP) { \
    if ((NTP) < 48) { \
        int j_ = (NTP) * 16 + jc; \
        float w2v_ = w2L[j_]; \
        float t0_ = tpL[j_], t1_ = tpL[H_ + j_], t2_ = tpL[2 * H_ + j_]; \
        _Pragma("unroll") \
        for (int r_ = 0; r_ < 4; ++r_) { \
            float xv_ = ((p0[r_] + p1[r_]) + (p2[r_] + p3[r_])) + (p4[r_] + p5[r_]); \
            la0[r_] += gelu_f(xv_ + t0_) * w2v_; \
            la1[r_] += gelu_f(xv_ + t1_) * w2v_; \
            la2[r_] += gelu_f(xv_ + t2_) * w2v_; \
        } \
    } else if (jc < 12) { \
        float bb_ = nb1[jc]; \
        _Pragma("unroll") \
        for (int r_ = 0; r_ < 4; ++r_) { \
            float xv_ = ((p0[r_] + p1[r_]) + (p2[r_] + p3[r_])) + (p4[r_] + p5[r_]); \
            int tl_ = (wave << 4) + ((lane >> 4) << 2) + r_; \
            h1L[tl_][jc] = gelu_f(xv_ + bb_); \
        } \
    } }

    STAGE(nt0, 0);
    __syncthreads();               // vmcnt(0) drain + barrier: tile 0 ready

    int cur = 0;
    for (int it = 0; it < NNT; ++it) {
        int nt = nt0 + it; if (nt >= NNT) nt -= NNT;
        if (it + 1 < NNT) {        // async prefetch next tile into other buffer
            int ntn = nt + 1; if (ntn >= NNT) ntn -= NNT;
            STAGE(ntn, cur ^ 1);
        }

        // deferred epilogue of tile it-1: independent VALU, overlays the
        // ds_read waits / MFMA issue of the current tile.
        if (ntprev >= 0) EPILOGUE(ntprev);

        const bf16x8* bp = (const bf16x8*)&Bst[cur][0];
        f32x4 c0 = {0,0,0,0}, c1 = {0,0,0,0}, c2 = {0,0,0,0},
              c3 = {0,0,0,0}, c4 = {0,0,0,0}, c5 = {0,0,0,0};
        #pragma unroll
        for (int ks = 0; ks < NKS; ++ks) {
            bf16x8 b1 = bp[(ks * 3 + 0) * 64 + lane];
            bf16x8 b2 = bp[(ks * 3 + 1) * 64 + lane];
            bf16x8 b3 = bp[(ks * 3 + 2) * 64 + lane];
            // 6 independent accumulator chains (R13 lesson: never chain these)
            c0 = __builtin_amdgcn_mfma_f32_16x16x32_bf16(a1[ks], b1, c0, 0, 0, 0);
            c1 = __builtin_amdgcn_mfma_f32_16x16x32_bf16(a1[ks], b2, c1, 0, 0, 0);
            c2 = __builtin_amdgcn_mfma_f32_16x16x32_bf16(a2[ks], b1, c2, 0, 0, 0);
            c3 = __builtin_amdgcn_mfma_f32_16x16x32_bf16(a2[ks], b2, c3, 0, 0, 0);
            c4 = __builtin_amdgcn_mfma_f32_16x16x32_bf16(a1[ks], b3, c4, 0, 0, 0);
            c5 = __builtin_amdgcn_mfma_f32_16x16x32_bf16(a3[ks], b1, c5, 0, 0, 0);
        }
        p0 = c0; p1 = c1; p2 = c2; p3 = c3; p4 = c4; p5 = c5; ntprev = nt;

        __syncthreads();           // drains prefetch vmcnt + flips buffer
        cur ^= 1;
    }
    EPILOGUE(ntprev);              // drain last tile

    // ---- finish logits: butterfly over the 16 j-columns held by a lane group
    float rb2m = wsF[WS_RB2M];
    #pragma unroll
    for (int r = 0; r < 4; ++r) {
        float v0 = la0[r], v1 = la1[r], v2 = la2[r];
        #pragma unroll
        for (int off = 1; off < 16; off <<= 1) {
            v0 += __shfl_xor(v0, off, 64);
            v1 += __shfl_xor(v1, off, 64);
            v2 += __shfl_xor(v2, off, 64);
        }
        if (jc == 0) {
            int tl = (wave << 4) + ((lane >> 4) << 2) + r;
            logitsL[tl][0] = v0 + rb2m;
            logitsL[tl][1] = v1 + rb2m;
            logitsL[tl][2] = v2 + rb2m;
        }
    }
    __syncthreads();

    // ---- phase 3: noise MLP layer 2, noisy logits, top-2, softmax, entropy
    float temp = wsF[WS_TEMP];
    for (int idx = tid; idx < TPB * E_; idx += 256) {
        int t = idx / E_, e = idx - t * E_;
        float s = nb2[e];
        #pragma unroll
        for (int i2 = 0; i2 < 12; ++i2) s = fmaf(h1L[t][i2], nw2[i2 * E_ + e], s);
        float nsc = softplus_f(softplus_f(s));
        int ety = expert_types[e];
        noisyL[t][e] = logitsL[t][ety] + ((ety == 1) ? 0.3f : 0.0f)
                     + temp * (noise[(size_t)(tok0 + t) * E_ + e] * nsc);
    }
    __syncthreads();
    if (tid < TPB) {
        int t = tid;
        float v1 = -1e30f; int i1 = 0;
        #pragma unroll
        for (int e = 0; e < E_; ++e) {
            float v = noisyL[t][e];
            if (v > v1) { v1 = v; i1 = e; }
        }
        float v2 = -1e30f; int i2 = 0;
        #pragma unroll
        for (int e = 0; e < E_; ++e) {
            if (e == i1) continue;
            float v = noisyL[t][e];
            if (v > v2) { v2 = v; i2 = e; }
        }
        float e2 = expf(v2 - v1);
        float den = 1.0f + e2;
        float p1s = 1.0f / den, p2s = e2 / den;
        psL[t][0] = p1s; psL[t][1] = p2s;
        isL[t][0] = i1; isL[t][1] = i2;
        entL[t] = -(p1s * logf(p1s + 1e-8f) + p2s * logf(p2s + 1e-8f));
        atomicAdd(&loadL[i1], 1u);
        atomicAdd(&loadL[i2], 1u);
    }
    __syncthreads();
    for (int idx = tid; idx < TPB * E_; idx += 256) {
        int t = idx / E_, e = idx - t * E_;
        float v = 0.f;
        if (e == isL[t][0])      v = psL[t][0];
        else if (e == isL[t][1]) v = psL[t][1];
        out[(size_t)tok0 * E_ + idx] = v;
    }
    if (tid < TPB * 2) {
        int t = tid >> 1, s = tid & 1;
        out[(size_t)NTOK * E_ + (size_t)(tok0 + t) * 2 + s] = (float)isL[t][s];
    }
    if (tid == 0) {
        float es = 0.f;
        #pragma unroll
        for (int tt = 0; tt < TPB; ++tt) es += entL[tt];
        atomicAdd(&wsF[WS_ENT], es);
        unsigned* lu = (unsigned*)(wsF + WS_LOAD);
        #pragma unroll
        for (int e = 0; e < E_; ++e)
            if (loadL[e]) atomicAdd(&lu[e], loadL[e]);
    }
}

__global__ void finalize_kernel(const float* __restrict__ wsF,
                                float* __restrict__ out)
{
    if (threadIdx.x == 0 && blockIdx.x == 0) {
        const unsigned* lu = (const unsigned*)(wsF + WS_LOAD);
        double m = 0.0, l[E_];
        #pragma unroll
        for (int e = 0; e < E_; ++e) { l[e] = (double)lu[e]; m += l[e]; }
        m /= (double)E_;
        double var = 0.0;
        #pragma unroll
        for (int e = 0; e < E_; ++e) { double d = l[e] - m; var += d * d; }
        var /= (double)(E_ - 1);
        double stdl = sqrt(var);
        // std(importance) == 0 exactly (top-2 always picks 2 of 6)
        double ent = (double)wsF[WS_ENT] / (double)NTOK;
        out[(size_t)NTOK * E_ + (size_t)NTOK * 2] = (float)(0.1 * ent + 0.2 * stdl);
    }
}

extern "C" void kernel_launch(void* const* d_in, const int* in_sizes, int n_in,
                              void* d_out, int out_size, void* d_ws, size_t ws_size,
                              hipStream_t stream)
{
    const float* x            = (const float*)d_in[0];
    const float* noise        = (const float*)d_in[1];
    const int*   expert_types = (const int*)  d_in[2];
    const float* type_emb     = (const float*)d_in[3];
    const float* nw1          = (const float*)d_in[4];
    const float* nb1          = (const float*)d_in[5];
    const float* nw2          = (const float*)d_in[6];
    const float* nb2          = (const float*)d_in[7];
    const float* rw1          = (const float*)d_in[8];
    const float* rb1          = (const float*)d_in[9];
    const float* rw2          = (const float*)d_in[10];
    const float* rb2          = (const float*)d_in[11];
    const float* temperature  = (const float*)d_in[12];
    float* out = (float*)d_out;
    float* wsF = (float*)d_ws;

    prep_kernel<<<NNT + 10, 256, 0, stream>>>(type_emb, rw1, rb1, rw2, rb2,
                                              temperature, nw1, wsF);
    router_mfma<<<NBLK, 256, 0, stream>>>(x, noise, expert_types,
                                          nb1, nw2, nb2, wsF, out);
    finalize_kernel<<<1, 64, 0, stream>>>(wsF, out);
}

// Round 15
// 147.894 us; speedup vs baseline: 2.0891x; 1.0573x over previous
//
#include <hip/hip_runtime.h>
#include <math.h>

#define B_ 8
#define T_ 4096
#define D_ 192
#define E_ 6
#define H_ 768            // 4*D
#define NTOK (B_*T_)      // 32768
#define NT 3              // expert types
#define TPB 64            // tokens per block
#define NBLK (NTOK/TPB)   // 512
#define NNT 49            // 48 rw1 column-tiles + 1 padded nw1 tile
#define NKS 6             // K steps of 32 (K=192)

// ws float-offset layout
#define WS_TPART 0        // 3*768 (rb1 folded in)
#define WS_W2M   2304     // 768
#define WS_TEMP  3072
#define WS_RB2M  3073
#define WS_ENT   3074
#define WS_LOAD  3075     // 6 uints
#define WS_BP    4096     // bf16 fragment pack: 49 * 9216 ushorts (903 KB)

typedef float  f32x4  __attribute__((ext_vector_type(4)));
typedef short  bf16x8 __attribute__((ext_vector_type(8)));

__device__ __forceinline__ ushort bf16rn(float f) {   // round-to-nearest-even bf16
    unsigned u = __float_as_uint(f);
    return (ushort)((u + 0x7FFFu + ((u >> 16) & 1u)) >> 16);
}

// async global->LDS, 16B per lane (dest = wave-uniform base + lane*16)
__device__ __forceinline__ void gll16(const void* g, void* lds) {
    __builtin_amdgcn_global_load_lds(
        (const __attribute__((address_space(1))) unsigned*)g,
        (__attribute__((address_space(3))) unsigned*)lds, 16, 0, 0);
}

// Fast erf (Abramowitz-Stegun 7.1.26): |err| <= 1.5e-7 (validated R4-R14).
__device__ __forceinline__ float gelu_f(float v) {
    float x  = v * 0.70710678118654752440f;
    float ax = fabsf(x);
    float t  = __builtin_amdgcn_rcpf(fmaf(0.3275911f, ax, 1.0f));
    float y  = t * fmaf(t, fmaf(t, fmaf(t, fmaf(t, 1.061405429f, -1.453152027f),
                                         1.421413741f), -0.284496736f), 0.254829592f);
    float em = __expf(-ax * ax);
    float er = fmaf(-y, em, 1.0f);
    er = copysignf(er, x);
    return 0.5f * v * (1.0f + er);
}
__device__ __forceinline__ float softplus_f(float x) {
    return fmaxf(x, 0.0f) + log1pf(expf(-fabsf(x)));
}

// prep: blocks 0..48 pack B fragments (3-way bf16 split, MFMA lane order);
// blocks 49..57 tpart (unroll 8: ~8 loads in flight on the serial k-loop,
// which was L2-latency-bound at ~8-15us); block 58 w2m + scalars.
__global__ __launch_bounds__(256) void prep_kernel(
    const float* __restrict__ type_emb,    // (3, 384)
    const float* __restrict__ rw1,         // (576, 768)
    const float* __restrict__ rb1,         // (768)
    const float* __restrict__ rw2,         // (768, 6)
    const float* __restrict__ rb2,         // (6)
    const float* __restrict__ temperature, // (1)
    const float* __restrict__ nw1,         // (192, 12)
    float* __restrict__ wsF)
{
    int blk = blockIdx.x, tid = threadIdx.x;
    if (blk < NNT) {
        int nt = blk;
        ushort* Bp = (ushort*)(wsF + WS_BP);
        int col = tid & 15;                         // coalesced reads: 16 cols/row
        for (int kr = tid >> 4; kr < D_; kr += 16) {
            float a;
            if (nt < 48) a = rw1[(size_t)kr * H_ + nt * 16 + col];
            else         a = (col < 12) ? nw1[kr * 12 + col] : 0.0f;
            ushort s1 = bf16rn(a);  float f1 = __uint_as_float((unsigned)s1 << 16);
            float r1 = a - f1;
            ushort s2 = bf16rn(r1); float f2 = __uint_as_float((unsigned)s2 << 16);
            float r2 = r1 - f2;
            ushort s3 = bf16rn(r2);
            // B-frag layout: lane l holds B[k= ks*32+(l>>4)*8+i][col= l&15]
            int ks = kr >> 5, kg = (kr >> 3) & 3, i = kr & 7;
            int l  = (kg << 4) | col;
            size_t base = (size_t)nt * 9216 + (size_t)((ks * 3) * 64 + l) * 8 + i;
            Bp[base]        = s1;                   // spl 0
            Bp[base + 512]  = s2;                   // spl 1 (+64 lanes*8)
            Bp[base + 1024] = s3;                   // spl 2
        }
    } else if (blk < NNT + 9) {
        int o = (blk - NNT) * 256 + tid;            // 0..2303
        int c = o / H_, j = o % H_;
        float s = rb1[j];
        const float* te = type_emb + c * (2 * D_);
        #pragma unroll 8
        for (int k = 0; k < 2 * D_; ++k)
            s = fmaf(te[k], rw1[(size_t)(D_ + k) * H_ + j], s);
        wsF[WS_TPART + o] = s;
    } else {
        for (int j = tid; j < H_; j += 256) {
            float s = 0.f;
            #pragma unroll
            for (int e = 0; e < E_; ++e) s += rw2[(size_t)j * E_ + e];
            wsF[WS_W2M + j] = s * (1.0f / 6.0f);
        }
        if (tid == 0) {
            float decay = (float)pow(0.95, (double)(T_ / 100));   // 0.95^40
            float tv = temperature[0] * decay;
            wsF[WS_TEMP] = fminf(fmaxf(tv, 0.05f), 3.0f);
            float rs = 0.f;
            #pragma unroll
            for (int e = 0; e < E_; ++e) rs += rb2[e];
            wsF[WS_RB2M] = rs * (1.0f / 6.0f);
            wsF[WS_ENT] = 0.f;
            unsigned* lu = (unsigned*)(wsF + WS_LOAD);
            #pragma unroll
            for (int e = 0; e < E_; ++e) lu[e] = 0u;
        }
    }
}

// R15: counted-vmcnt pipeline (T4). R8-R14 invariant 122-135us = ~6400cy/tile
// vs ~1000cy of work: the stall is __syncthreads' implicit vmcnt(0) draining
// the just-issued L2 stage-loads every tile, with barrier-lockstep sync'ing
// the load bursts of all 512 blocks. Fix: triple buffer, prefetch depth 2,
// RAW s_barrier + per-wave counted vmcnt (waves 0,1 issue 5 chunks/tile ->
// vmcnt(5); waves 2,3 -> vmcnt(4)), so next-next tile's loads stay in flight
// across the barrier. Safety: each wave's wait covers its OWN chunk writes to
// the tile read next; barrier then guarantees all waves' chunks landed.
// Buffer overwrite hazard: slot (it+2)%3 was last read at it-1; its ds_reads
// are in regs before it-1's barrier (compiler lgkmcnt before MFMA use). Full
// __syncthreads only before phase 3 (h1L/logitsL).
__global__ __launch_bounds__(256, 2) void router_mfma(
    const float* __restrict__ x,            // (32768, 192)
    const float* __restrict__ noise,        // (32768, 6)
    const int*   __restrict__ expert_types, // (6)
    const float* __restrict__ nb1,          // (12)
    const float* __restrict__ nw2,          // (12, 6)
    const float* __restrict__ nb2,          // (6)
    float* __restrict__ wsF,
    float* __restrict__ out)
{
    __shared__ float4 Bst[3][1152];     // 54 KB triple-buffered B tile
    __shared__ float tpL[NT * H_];      // 9 KB
    __shared__ float w2L[H_];           // 3 KB
    __shared__ float logitsL[TPB][NT];
    __shared__ float h1L[TPB][12];
    __shared__ float noisyL[TPB][E_];
    __shared__ float psL[TPB][2];
    __shared__ int   isL[TPB][2];
    __shared__ float entL[TPB];
    __shared__ unsigned loadL[E_];

    int tid = threadIdx.x;
    int wave = tid >> 6, lane = tid & 63;
    int tok0 = blockIdx.x * TPB;
    int jc = lane & 15;

    for (int i = tid; i < NT * H_; i += 256) tpL[i] = wsF[WS_TPART + i];
    for (int i = tid; i < H_; i += 256)      w2L[i] = wsF[WS_W2M + i];
    if (tid < E_) loadL[tid] = 0u;

    // ---- A fragments: lane holds token row tok0+wave*16+jc, k=ks*32+(lane>>4)*8+i.
    int tok = tok0 + (wave << 4) + jc;
    int kg  = (lane >> 4) << 3;
    bf16x8 a1[NKS], a2[NKS], a3[NKS];
    #pragma unroll
    for (int ks = 0; ks < NKS; ++ks) {
        const float* xp = x + (size_t)tok * D_ + ks * 32 + kg;
        float4 v0 = *(const float4*)xp;
        float4 v1 = *(const float4*)(xp + 4);
        float f[8] = {v0.x, v0.y, v0.z, v0.w, v1.x, v1.y, v1.z, v1.w};
        #pragma unroll
        for (int i = 0; i < 8; ++i) {
            float a = f[i];
            ushort s1 = bf16rn(a);  float f1 = __uint_as_float((unsigned)s1 << 16);
            float r1 = a - f1;
            ushort s2 = bf16rn(r1); float f2 = __uint_as_float((unsigned)s2 << 16);
            float r2 = r1 - f2;
            a1[ks][i] = (short)s1; a2[ks][i] = (short)s2; a3[ks][i] = (short)bf16rn(r2);
        }
    }

    float la0[4] = {0,0,0,0}, la1[4] = {0,0,0,0}, la2[4] = {0,0,0,0};
    const ushort* Bp = (const ushort*)(wsF + WS_BP);
    int nt0 = blockIdx.x % NNT;    // decorrelate co-XCD blocks (R6 lesson)

    // async staging: 18 chunks of 64 float4 per tile; wave w issues chunks
    // {w, w+4, w+8, w+12} and (w<2) chunk 16+w -> waves 0,1: 5; waves 2,3: 4.
#define STAGE(ntv, bufv) { \
    const float4* sp_ = (const float4*)(Bp + (size_t)(ntv) * 9216); \
    float4* dp_ = &Bst[bufv][0]; \
    _Pragma("unroll") \
    for (int c_ = wave; c_ < 16; c_ += 4) \
        gll16(sp_ + (c_ * 64 + lane), dp_ + c_ * 64); \
    if (wave < 2) gll16(sp_ + ((16 + wave) * 64 + lane), dp_ + (16 + wave) * 64); \
}
    // counted wait: leave exactly one tile's worth of this wave's loads in flight
#define WAIT_ONE_TILE() { \
    if (wave < 2) asm volatile("s_waitcnt vmcnt(5)" ::: "memory"); \
    else          asm volatile("s_waitcnt vmcnt(4)" ::: "memory"); \
    __builtin_amdgcn_sched_barrier(0); }

    // deferred-epilogue state: prev tile's 6 accumulators + id (24 VGPR)
    f32x4 p0 = {0,0,0,0}, p1 = {0,0,0,0}, p2 = {0,0,0,0},
          p3 = {0,0,0,0}, p4 = {0,0,0,0}, p5 = {0,0,0,0};
    int ntprev = -1;

#define EPILOGUE(NTP) { \
    if ((NTP) < 48) { \
        int j_ = (NTP) * 16 + jc; \
        float w2v_ = w2L[j_]; \
        float t0_ = tpL[j_], t1_ = tpL[H_ + j_], t2_ = tpL[2 * H_ + j_]; \
        _Pragma("unroll") \
        for (int r_ = 0; r_ < 4; ++r_) { \
            float xv_ = ((p0[r_] + p1[r_]) + (p2[r_] + p3[r_])) + (p4[r_] + p5[r_]); \
            la0[r_] += gelu_f(xv_ + t0_) * w2v_; \
            la1[r_] += gelu_f(xv_ + t1_) * w2v_; \
            la2[r_] += gelu_f(xv_ + t2_) * w2v_; \
        } \
    } else if (jc < 12) { \
        float bb_ = nb1[jc]; \
        _Pragma("unroll") \
        for (int r_ = 0; r_ < 4; ++r_) { \
            float xv_ = ((p0[r_] + p1[r_]) + (p2[r_] + p3[r_])) + (p4[r_] + p5[r_]); \
            int tl_ = (wave << 4) + ((lane >> 4) << 2) + r_; \
            h1L[tl_][jc] = gelu_f(xv_ + bb_); \
        } \
    } }

    // prologue: fill buffers 0 and 1; wait until tile 0 landed (tile 1 stays
    // in flight); drain the tpL/w2L ds_writes; barrier.
    STAGE(nt0, 0);
    { int nt1 = nt0 + 1; if (nt1 >= NNT) nt1 -= NNT; STAGE(nt1, 1); }
    asm volatile("s_waitcnt lgkmcnt(0)" ::: "memory");
    WAIT_ONE_TILE();
    __builtin_amdgcn_s_barrier();

    for (int it = 0; it < NNT; ++it) {
        int nt = nt0 + it; if (nt >= NNT) nt -= NNT;
        if (it + 2 < NNT) {        // prefetch depth 2 into the free slot
            int ntn = nt + 2; if (ntn >= NNT) ntn -= NNT;
            STAGE(ntn, (it + 2) % 3);
        }

        // deferred epilogue of tile it-1 (independent VALU)
        if (ntprev >= 0) EPILOGUE(ntprev);

        const bf16x8* bp = (const bf16x8*)&Bst[it % 3][0];
        f32x4 c0 = {0,0,0,0}, c1 = {0,0,0,0}, c2 = {0,0,0,0},
              c3 = {0,0,0,0}, c4 = {0,0,0,0}, c5 = {0,0,0,0};
        #pragma unroll
        for (int ks = 0; ks < NKS; ++ks) {
            bf16x8 b1 = bp[(ks * 3 + 0) * 64 + lane];
            bf16x8 b2 = bp[(ks * 3 + 1) * 64 + lane];
            bf16x8 b3 = bp[(ks * 3 + 2) * 64 + lane];
            // 6 independent accumulator chains (R13 lesson: never chain these)
            c0 = __builtin_amdgcn_mfma_f32_16x16x32_bf16(a1[ks], b1, c0, 0, 0, 0);
            c1 = __builtin_amdgcn_mfma_f32_16x16x32_bf16(a1[ks], b2, c1, 0, 0, 0);
            c2 = __builtin_amdgcn_mfma_f32_16x16x32_bf16(a2[ks], b1, c2, 0, 0, 0);
            c3 = __builtin_amdgcn_mfma_f32_16x16x32_bf16(a2[ks], b2, c3, 0, 0, 0);
            c4 = __builtin_amdgcn_mfma_f32_16x16x32_bf16(a1[ks], b3, c4, 0, 0, 0);
            c5 = __builtin_amdgcn_mfma_f32_16x16x32_bf16(a3[ks], b1, c5, 0, 0, 0);
        }
        p0 = c0; p1 = c1; p2 = c2; p3 = c3; p4 = c4; p5 = c5; ntprev = nt;

        // counted wait (NOT vmcnt(0)): tile it+1's loads landed; it+2's stay
        // in flight across the raw barrier.
        if (it + 2 < NNT) { WAIT_ONE_TILE(); }
        else { asm volatile("s_waitcnt vmcnt(0)" ::: "memory");
               __builtin_amdgcn_sched_barrier(0); }
        __builtin_amdgcn_s_barrier();
    }
    EPILOGUE(ntprev);              // drain last tile

    // ---- finish logits: butterfly over the 16 j-columns held by a lane group
    float rb2m = wsF[WS_RB2M];
    #pragma unroll
    for (int r = 0; r < 4; ++r) {
        float v0 = la0[r], v1 = la1[r], v2 = la2[r];
        #pragma unroll
        for (int off = 1; off < 16; off <<= 1) {
            v0 += __shfl_xor(v0, off, 64);
            v1 += __shfl_xor(v1, off, 64);
            v2 += __shfl_xor(v2, off, 64);
        }
        if (jc == 0) {
            int tl = (wave << 4) + ((lane >> 4) << 2) + r;
            logitsL[tl][0] = v0 + rb2m;
            logitsL[tl][1] = v1 + rb2m;
            logitsL[tl][2] = v2 + rb2m;
        }
    }
    __syncthreads();               // full drain before phase 3 (h1L/logitsL)

    // ---- phase 3: noise MLP layer 2, noisy logits, top-2, softmax, entropy
    float temp = wsF[WS_TEMP];
    for (int idx = tid; idx < TPB * E_; idx += 256) {
        int t = idx / E_, e = idx - t * E_;
        float s = nb2[e];
        #pragma unroll
        for (int i2 = 0; i2 < 12; ++i2) s = fmaf(h1L[t][i2], nw2[i2 * E_ + e], s);
        float nsc = softplus_f(softplus_f(s));
        int ety = expert_types[e];
        noisyL[t][e] = logitsL[t][ety] + ((ety == 1) ? 0.3f : 0.0f)
                     + temp * (noise[(size_t)(tok0 + t) * E_ + e] * nsc);
    }
    __syncthreads();
    if (tid < TPB) {
        int t = tid;
        float v1 = -1e30f; int i1 = 0;
        #pragma unroll
        for (int e = 0; e < E_; ++e) {
            float v = noisyL[t][e];
            if (v > v1) { v1 = v; i1 = e; }
        }
        float v2 = -1e30f; int i2 = 0;
        #pragma unroll
        for (int e = 0; e < E_; ++e) {
            if (e == i1) continue;
            float v = noisyL[t][e];
            if (v > v2) { v2 = v; i2 = e; }
        }
        float e2 = expf(v2 - v1);
        float den = 1.0f + e2;
        float p1s = 1.0f / den, p2s = e2 / den;
        psL[t][0] = p1s; psL[t][1] = p2s;
        isL[t][0] = i1; isL[t][1] = i2;
        entL[t] = -(p1s * logf(p1s + 1e-8f) + p2s * logf(p2s + 1e-8f));
        atomicAdd(&loadL[i1], 1u);
        atomicAdd(&loadL[i2], 1u);
    }
    __syncthreads();
    for (int idx = tid; idx < TPB * E_; idx += 256) {
        int t = idx / E_, e = idx - t * E_;
        float v = 0.f;
        if (e == isL[t][0])      v = psL[t][0];
        else if (e == isL[t][1]) v = psL[t][1];
        out[(size_t)tok0 * E_ + idx] = v;
    }
    if (tid < TPB * 2) {
        int t = tid >> 1, s = tid & 1;
        out[(size_t)NTOK * E_ + (size_t)(tok0 + t) * 2 + s] = (float)isL[t][s];
    }
    if (tid == 0) {
        float es = 0.f;
        #pragma unroll
        for (int tt = 0; tt < TPB; ++tt) es += entL[tt];
        atomicAdd(&wsF[WS_ENT], es);
        unsigned* lu = (unsigned*)(wsF + WS_LOAD);
        #pragma unroll
        for (int e = 0; e < E_; ++e)
            if (loadL[e]) atomicAdd(&lu[e], loadL[e]);
    }
}

__global__ void finalize_kernel(const float* __restrict__ wsF,
                                float* __restrict__ out)
{
    if (threadIdx.x == 0 && blockIdx.x == 0) {
        const unsigned* lu = (const unsigned*)(wsF + WS_LOAD);
        double m = 0.0, l[E_];
        #pragma unroll
        for (int e = 0; e < E_; ++e) { l[e] = (double)lu[e]; m += l[e]; }
        m /= (double)E_;
        double var = 0.0;
        #pragma unroll
        for (int e = 0; e < E_; ++e) { double d = l[e] - m; var += d * d; }
        var /= (double)(E_ - 1);
        double stdl = sqrt(var);
        // std(importance) == 0 exactly (top-2 always picks 2 of 6)
        double ent = (double)wsF[WS_ENT] / (double)NTOK;
        out[(size_t)NTOK * E_ + (size_t)NTOK * 2] = (float)(0.1 * ent + 0.2 * stdl);
    }
}

extern "C" void kernel_launch(void* const* d_in, const int* in_sizes, int n_in,
                              void* d_out, int out_size, void* d_ws, size_t ws_size,
                              hipStream_t stream)
{
    const float* x            = (const float*)d_in[0];
    const float* noise        = (const float*)d_in[1];
    const int*   expert_types = (const int*)  d_in[2];
    const float* type_emb     = (const float*)d_in[3];
    const float* nw1          = (const float*)d_in[4];
    const float* nb1          = (const float*)d_in[5];
    const float* nw2          = (const float*)d_in[6];
    const float* nb2          = (const float*)d_in[7];
    const float* rw1          = (const float*)d_in[8];
    const float* rb1          = (const float*)d_in[9];
    const float* rw2          = (const float*)d_in[10];
    const float* rb2          = (const float*)d_in[11];
    const float* temperature  = (const float*)d_in[12];
    float* out = (float*)d_out;
    float* wsF = (float*)d_ws;

    prep_kernel<<<NNT + 10, 256, 0, stream>>>(type_emb, rw1, rb1, rw2, rb2,
                                              temperature, nw1, wsF);
    router_mfma<<<NBLK, 256, 0, stream>>>(x, noise, expert_types,
                                          nb1, nw2, nb2, wsF, out);
    finalize_kernel<<<1, 64, 0, stream>>>(wsF, out);
}